// Round 4
// baseline (299.793 us; speedup 1.0000x reference)
//
#include <hip/hip_runtime.h>
#include <hip/hip_bf16.h>

// B=4, T=2048, D=768, H=12, DH=64, causal MHA + QKV/out projections.
// All inputs fp32; internals bf16 (threshold 8*bf16eps permits this).
//
// R4: attention rewrite — fixed-max base-2 softmax (M=32; deletes rmax
// shuffles, alpha, O-rescale; partials additive), row-sum l via MFMA with
// all-ones B-frag, 2-way key-split with paired q-tiles (j, 63-j) for
// uniform block cost (grid 1536). GEMMs unchanged from R3 (m97 structure).

#define BATCH  4
#define SEQ    2048
#define DMODEL 768
#define NH     12
#define DHEAD  64
static constexpr float SCALE_LOG2E = 0.125f * 1.4426950408889634f;

#define N_X  (8192 * 768)
#define N_WQ (2304 * 768)
#define N_WP (768 * 768)

typedef __bf16 v8bf __attribute__((ext_vector_type(8)));
typedef float  v4f  __attribute__((ext_vector_type(4)));

__device__ __forceinline__ v8bf cvt8(const float* __restrict__ p) {
    const float4 a = ((const float4*)p)[0];
    const float4 b = ((const float4*)p)[1];
    v8bf r;
    r[0] = (__bf16)a.x; r[1] = (__bf16)a.y; r[2] = (__bf16)a.z; r[3] = (__bf16)a.w;
    r[4] = (__bf16)b.x; r[5] = (__bf16)b.y; r[6] = (__bf16)b.z; r[7] = (__bf16)b.w;
    return r;
}

__device__ __forceinline__ void async_copy16(__bf16* lds, const __bf16* g) {
    __builtin_amdgcn_global_load_lds(
        (const __attribute__((address_space(1))) void*)g,
        (__attribute__((address_space(3))) void*)lds, 16, 0, 0);
}

// ---------------------------------------------------------------------------
// Kernel 0: fp32 -> bf16 convert of x, Wqkv, Wproj.
// ---------------------------------------------------------------------------
__global__ __launch_bounds__(256) void cvt_kernel(
        const float* __restrict__ x, const float* __restrict__ Wq,
        const float* __restrict__ Wp, __bf16* __restrict__ xb,
        __bf16* __restrict__ Wqb, __bf16* __restrict__ Wpb) {
    const long e = ((long)blockIdx.x * 256 + threadIdx.x) * 8;
    const float* src;
    __bf16* dst;
    if (e < N_X)             { src = x  + e;               dst = xb  + e; }
    else if (e < N_X + N_WQ) { src = Wq + (e - N_X);        dst = Wqb + (e - N_X); }
    else                     { src = Wp + (e - N_X - N_WQ); dst = Wpb + (e - N_X - N_WQ); }
    *(v8bf*)dst = cvt8(src);
}

// ---------------------------------------------------------------------------
// Kernel 1: qkv = xb @ Wqkvb^T (m97 structure, unchanged from R3).
// ---------------------------------------------------------------------------
__global__ __launch_bounds__(256) void qkv_gemm(
        const __bf16* __restrict__ xb, const __bf16* __restrict__ Wb,
        __bf16* __restrict__ Qb, __bf16* __restrict__ Kb, __bf16* __restrict__ Vtb) {
    __shared__ __bf16 As[128 * 32], Bs[128 * 32];
    const int lane = threadIdx.x & 63, wave = threadIdx.x >> 6;
    const int nb = blockIdx.x % 18, mb = blockIdx.x / 18;
    const int r16 = lane & 15, quad = lane >> 4;
    const int wm = (wave >> 1) * 64, wn = (wave & 1) * 64;
    const __bf16* Asrc = xb + (size_t)mb * 128 * DMODEL;
    const __bf16* Bsrc = Wb + (size_t)nb * 128 * DMODEL;

    v4f acc[4][4] = {};
    for (int k0 = 0; k0 < DMODEL; k0 += 32) {
#pragma unroll
        for (int p = 0; p < 2; ++p) {
            const int cb = p * 256 + wave * 64;
            const int c = cb + lane;
            const int row = c >> 2, sg = c & 3;
            async_copy16(&As[cb * 8], Asrc + (size_t)row * DMODEL + k0 + sg * 8);
            async_copy16(&Bs[cb * 8], Bsrc + (size_t)row * DMODEL + k0 + sg * 8);
        }
        __syncthreads();
        v8bf a[4], b[4];
#pragma unroll
        for (int i = 0; i < 4; ++i)
            a[i] = *(const v8bf*)&As[(wm + 16 * i + r16) * 32 + quad * 8];
#pragma unroll
        for (int j = 0; j < 4; ++j)
            b[j] = *(const v8bf*)&Bs[(wn + 16 * j + r16) * 32 + quad * 8];
#pragma unroll
        for (int i = 0; i < 4; ++i)
#pragma unroll
            for (int j = 0; j < 4; ++j)
                acc[i][j] = __builtin_amdgcn_mfma_f32_16x16x32_bf16(
                    a[i], b[j], acc[i][j], 0, 0, 0);
        __syncthreads();
    }

    const int seg = nb / 6;
    const int nl0 = (nb % 6) * 128 + wn;
#pragma unroll
    for (int j = 0; j < 4; ++j) {
        const int n = nl0 + 16 * j + r16;
        const int h = n >> 6, d = n & 63;
#pragma unroll
        for (int i = 0; i < 4; ++i) {
            const int mrow = mb * 128 + wm + 16 * i + quad * 4;
#pragma unroll
            for (int r = 0; r < 4; ++r) {
                const int m = mrow + r;
                const int bidx = m >> 11, t = m & (SEQ - 1);
                const size_t base = ((size_t)(bidx * NH + h)) * SEQ * DHEAD;
                if (seg == 0)
                    Qb[base + (size_t)t * DHEAD + d] = (__bf16)(acc[i][j][r] * SCALE_LOG2E);
                else if (seg == 1)
                    Kb[base + (size_t)t * DHEAD + d] = (__bf16)acc[i][j][r];
                else
                    Vtb[base + (size_t)d * SEQ + t] = (__bf16)acc[i][j][r];
            }
        }
    }
}

// ---------------------------------------------------------------------------
// Kernel 2: MFMA causal flash attention, R4 structure.
// Block = 4 waves: wave w -> q-tile (w>>1 ? 63-pair : pair), key parity w&1.
// Fixed-max softmax p=exp2(s-32); l via MFMA ones; additive partial merge.
// ---------------------------------------------------------------------------
__global__ __launch_bounds__(256) void attn_kernel(
        const __bf16* __restrict__ Qb, const __bf16* __restrict__ Kb,
        const __bf16* __restrict__ Vtb, __bf16* __restrict__ attnb) {
    // union: in-loop P tiles (4 waves x 32 x 72 bf16 = 18432 B)
    //        post-loop merge Om[2][32][68] f32 (17408 B) + Lm[2][32] (256 B)
    __shared__ __align__(16) char smem[18432];
    const int lane = threadIdx.x & 63;
    const int wave = threadIdx.x >> 6;
    const int bh   = blockIdx.x >> 5;          // [0,48)
    const int pair = blockIdx.x & 31;          // [0,32)
    const int qsel = wave >> 1;                // 0 -> tile pair, 1 -> tile 63-pair
    const int kpar = wave & 1;                 // key-chunk parity
    const int qt   = qsel ? (63 - pair) : pair;
    const int q0   = qt * 32;
    const int r16  = lane & 15;
    const int quad = lane >> 4;

    __bf16* Pl = ((__bf16*)smem) + wave * (32 * 72);

    const __bf16* Q  = Qb  + (size_t)bh * SEQ * DHEAD;
    const __bf16* K  = Kb  + (size_t)bh * SEQ * DHEAD;
    const __bf16* Vt = Vtb + (size_t)bh * DHEAD * SEQ;

    // Q A-fragments (both key-parity waves load the same — L1/L2 hit)
    v8bf aq[2][2];
#pragma unroll
    for (int i = 0; i < 2; ++i)
#pragma unroll
        for (int kk = 0; kk < 2; ++kk)
            aq[i][kk] = *(const v8bf*)(Q + (size_t)(q0 + 16 * i + r16) * DHEAD
                                         + kk * 32 + quad * 8);

    v8bf vones;
#pragma unroll
    for (int j = 0; j < 8; ++j) vones[j] = (__bf16)1.0f;

    v4f oacc[2][4] = {};
    v4f lacc[2] = {};

    const int tmax = q0 + 31;
    for (int k0 = kpar * 64; k0 <= tmax; k0 += 128) {
        // ---- QK^T ----
        v8bf bk[4][2];
#pragma unroll
        for (int s = 0; s < 4; ++s)
#pragma unroll
            for (int kk = 0; kk < 2; ++kk)
                bk[s][kk] = *(const v8bf*)(K + (size_t)(k0 + 16 * s + r16) * DHEAD
                                             + kk * 32 + quad * 8);
        v4f sc[2][4] = {};
#pragma unroll
        for (int kk = 0; kk < 2; ++kk)
#pragma unroll
            for (int i = 0; i < 2; ++i)
#pragma unroll
                for (int s = 0; s < 4; ++s)
                    sc[i][s] = __builtin_amdgcn_mfma_f32_16x16x32_bf16(
                        aq[i][kk], bk[s][kk], sc[i][s], 0, 0, 0);

        // ---- causal mask (diagonal chunks only) ----
        if (k0 + 63 > q0) {
#pragma unroll
            for (int i = 0; i < 2; ++i)
#pragma unroll
                for (int s = 0; s < 4; ++s)
#pragma unroll
                    for (int r = 0; r < 4; ++r) {
                        const int row = q0 + 16 * i + quad * 4 + r;
                        const int col = k0 + 16 * s + r16;
                        if (col > row) sc[i][s][r] = -1e30f;
                    }
        }

        // ---- fixed-max softmax: p = exp2(s - 32) ----
#pragma unroll
        for (int i = 0; i < 2; ++i)
#pragma unroll
            for (int s = 0; s < 4; ++s)
#pragma unroll
                for (int r = 0; r < 4; ++r)
                    sc[i][s][r] = __builtin_exp2f(sc[i][s][r] - 32.0f);

        // ---- P: C-layout regs -> LDS (bf16) ----
#pragma unroll
        for (int i = 0; i < 2; ++i)
#pragma unroll
            for (int s = 0; s < 4; ++s)
#pragma unroll
                for (int r = 0; r < 4; ++r)
                    Pl[(16 * i + quad * 4 + r) * 72 + 16 * s + r16] = (__bf16)sc[i][s][r];
        __builtin_amdgcn_s_waitcnt(0);   // wave-internal LDS ordering

        // ---- PV + l (ones-MFMA) ----
        v8bf ap[2][2];
#pragma unroll
        for (int i = 0; i < 2; ++i)
#pragma unroll
            for (int kk = 0; kk < 2; ++kk)
                ap[i][kk] = *(const v8bf*)&Pl[(16 * i + r16) * 72 + kk * 32 + quad * 8];
        v8bf bv[2][4];
#pragma unroll
        for (int kk = 0; kk < 2; ++kk)
#pragma unroll
            for (int n = 0; n < 4; ++n)
                bv[kk][n] = *(const v8bf*)(Vt + (size_t)(16 * n + r16) * SEQ
                                             + k0 + kk * 32 + quad * 8);
#pragma unroll
        for (int kk = 0; kk < 2; ++kk)
#pragma unroll
            for (int i = 0; i < 2; ++i) {
#pragma unroll
                for (int n = 0; n < 4; ++n)
                    oacc[i][n] = __builtin_amdgcn_mfma_f32_16x16x32_bf16(
                        ap[i][kk], bv[kk][n], oacc[i][n], 0, 0, 0);
                lacc[i] = __builtin_amdgcn_mfma_f32_16x16x32_bf16(
                    ap[i][kk], vones, lacc[i], 0, 0, 0);
            }
    }

    // ---- additive partial merge: kpar=1 writes, kpar=0 adds + epilogue ----
    __syncthreads();
    float* Om = (float*)smem;                  // [2][32][68]
    float* Lm = (float*)(smem + 17408);        // [2][32]
    if (kpar == 1) {
#pragma unroll
        for (int i = 0; i < 2; ++i) {
#pragma unroll
            for (int n = 0; n < 4; ++n)
#pragma unroll
                for (int r = 0; r < 4; ++r)
                    Om[(qsel * 32 + 16 * i + quad * 4 + r) * 68 + 16 * n + r16] =
                        oacc[i][n][r];
            if (r16 == 0)
#pragma unroll
                for (int r = 0; r < 4; ++r)
                    Lm[qsel * 32 + 16 * i + quad * 4 + r] = lacc[i][r];
        }
    }
    __syncthreads();
    if (kpar == 0) {
        const int b = bh / NH, h = bh - b * NH;
#pragma unroll
        for (int i = 0; i < 2; ++i) {
#pragma unroll
            for (int r = 0; r < 4; ++r) {
                const float l = lacc[i][r] + Lm[qsel * 32 + 16 * i + quad * 4 + r];
                const float inv = 1.0f / l;
                const int t = q0 + 16 * i + quad * 4 + r;
#pragma unroll
                for (int n = 0; n < 4; ++n) {
                    const int d = 16 * n + r16;
                    const float o = oacc[i][n][r] +
                        Om[(qsel * 32 + 16 * i + quad * 4 + r) * 68 + 16 * n + r16];
                    attnb[((size_t)(b * SEQ + t)) * DMODEL + h * DHEAD + d] =
                        (__bf16)(o * inv);
                }
            }
        }
    }
}

// ---------------------------------------------------------------------------
// Kernel 3: out = attnb @ Wprojb^T + bproj (m97 structure, unchanged).
// ---------------------------------------------------------------------------
__global__ __launch_bounds__(256) void proj_gemm(
        const __bf16* __restrict__ Ab, const __bf16* __restrict__ Wb,
        const float* __restrict__ bias, float* __restrict__ out) {
    __shared__ __bf16 As[128 * 32], Bs[128 * 32];
    const int lane = threadIdx.x & 63, wave = threadIdx.x >> 6;
    const int nb = blockIdx.x % 6, mb = blockIdx.x / 6;
    const int r16 = lane & 15, quad = lane >> 4;
    const int wm = (wave >> 1) * 64, wn = (wave & 1) * 64;
    const __bf16* Asrc = Ab + (size_t)mb * 128 * DMODEL;
    const __bf16* Bsrc = Wb + (size_t)nb * 128 * DMODEL;

    v4f acc[4][4] = {};
    for (int k0 = 0; k0 < DMODEL; k0 += 32) {
#pragma unroll
        for (int p = 0; p < 2; ++p) {
            const int cb = p * 256 + wave * 64;
            const int c = cb + lane;
            const int row = c >> 2, sg = c & 3;
            async_copy16(&As[cb * 8], Asrc + (size_t)row * DMODEL + k0 + sg * 8);
            async_copy16(&Bs[cb * 8], Bsrc + (size_t)row * DMODEL + k0 + sg * 8);
        }
        __syncthreads();
        v8bf a[4], b[4];
#pragma unroll
        for (int i = 0; i < 4; ++i)
            a[i] = *(const v8bf*)&As[(wm + 16 * i + r16) * 32 + quad * 8];
#pragma unroll
        for (int j = 0; j < 4; ++j)
            b[j] = *(const v8bf*)&Bs[(wn + 16 * j + r16) * 32 + quad * 8];
#pragma unroll
        for (int i = 0; i < 4; ++i)
#pragma unroll
            for (int j = 0; j < 4; ++j)
                acc[i][j] = __builtin_amdgcn_mfma_f32_16x16x32_bf16(
                    a[i], b[j], acc[i][j], 0, 0, 0);
        __syncthreads();
    }

#pragma unroll
    for (int j = 0; j < 4; ++j) {
        const int n = nb * 128 + wn + 16 * j + r16;
        const float bv = bias[n];
#pragma unroll
        for (int i = 0; i < 4; ++i) {
            const int mrow = mb * 128 + wm + 16 * i + quad * 4;
#pragma unroll
            for (int r = 0; r < 4; ++r)
                out[(size_t)(mrow + r) * DMODEL + n] = acc[i][j][r] + bv;
        }
    }
}

// ---------------------------------------------------------------------------
extern "C" void kernel_launch(void* const* d_in, const int* in_sizes, int n_in,
                              void* d_out, int out_size, void* d_ws, size_t ws_size,
                              hipStream_t stream) {
    const float* x     = (const float*)d_in[0];
    const float* Wqkv  = (const float*)d_in[1];
    const float* Wproj = (const float*)d_in[2];
    const float* bproj = (const float*)d_in[3];
    float* out = (float*)d_out;

    char* ws = (char*)d_ws;
    const size_t tsz = (size_t)BATCH * NH * SEQ * DHEAD * sizeof(__bf16); // 12.58 MB
    __bf16* Qb    = (__bf16*)(ws);
    __bf16* Kb    = (__bf16*)(ws + tsz);
    __bf16* Vtb   = (__bf16*)(ws + 2 * tsz);          // [B,H,DH,T]
    __bf16* xb    = (__bf16*)(ws + 3 * tsz);          // aliased with attnb:
    __bf16* attnb = (__bf16*)(ws + 3 * tsz);          // xb dead before attn writes
    __bf16* Wqb   = (__bf16*)(ws + 4 * tsz);
    __bf16* Wpb   = (__bf16*)(ws + 4 * tsz + (size_t)N_WQ * 2);

    cvt_kernel<<<dim3((N_X + N_WQ + N_WP) / (8 * 256)), dim3(256), 0, stream>>>(
        x, Wqkv, Wproj, xb, Wqb, Wpb);
    qkv_gemm<<<dim3(64 * 18), dim3(256), 0, stream>>>(xb, Wqb, Qb, Kb, Vtb);
    attn_kernel<<<dim3(48 * 32), dim3(256), 0, stream>>>(Qb, Kb, Vtb, attnb);
    proj_gemm<<<dim3(64 * 6), dim3(256), 0, stream>>>(attnb, Wpb, bproj, out);
}

// Round 5
// 239.592 us; speedup vs baseline: 1.2513x; 1.2513x over previous
//
#include <hip/hip_runtime.h>
#include <hip/hip_bf16.h>

// B=4, T=2048, D=768, H=12, DH=64, causal MHA + QKV/out projections.
// All inputs fp32; internals bf16 (threshold 8*bf16eps permits this).
//
// R5: attention = 128-row blocks (R3 locality) + K/V LDS staging via
// global_load_lds + software-pipelined prefetch (frags in regs, next chunk's
// asyncs issued before compute) + XCD-aware swizzle (all q-blocks of a bh on
// one XCD; K/V L2-resident) + fixed-max softmax & ones-MFMA row-sum (R4 keeps).
// GEMMs unchanged (m97 structure).

#define BATCH  4
#define SEQ    2048
#define DMODEL 768
#define NH     12
#define DHEAD  64
static constexpr float SCALE_LOG2E = 0.125f * 1.4426950408889634f;

#define N_X  (8192 * 768)
#define N_WQ (2304 * 768)
#define N_WP (768 * 768)

typedef __bf16 v8bf __attribute__((ext_vector_type(8)));
typedef float  v4f  __attribute__((ext_vector_type(4)));

__device__ __forceinline__ v8bf cvt8(const float* __restrict__ p) {
    const float4 a = ((const float4*)p)[0];
    const float4 b = ((const float4*)p)[1];
    v8bf r;
    r[0] = (__bf16)a.x; r[1] = (__bf16)a.y; r[2] = (__bf16)a.z; r[3] = (__bf16)a.w;
    r[4] = (__bf16)b.x; r[5] = (__bf16)b.y; r[6] = (__bf16)b.z; r[7] = (__bf16)b.w;
    return r;
}

__device__ __forceinline__ void async_copy16(__bf16* lds, const __bf16* g) {
    __builtin_amdgcn_global_load_lds(
        (const __attribute__((address_space(1))) void*)g,
        (__attribute__((address_space(3))) void*)lds, 16, 0, 0);
}

// ---------------------------------------------------------------------------
// Kernel 0: fp32 -> bf16 convert of x, Wqkv, Wproj.
// ---------------------------------------------------------------------------
__global__ __launch_bounds__(256) void cvt_kernel(
        const float* __restrict__ x, const float* __restrict__ Wq,
        const float* __restrict__ Wp, __bf16* __restrict__ xb,
        __bf16* __restrict__ Wqb, __bf16* __restrict__ Wpb) {
    const long e = ((long)blockIdx.x * 256 + threadIdx.x) * 8;
    const float* src;
    __bf16* dst;
    if (e < N_X)             { src = x  + e;               dst = xb  + e; }
    else if (e < N_X + N_WQ) { src = Wq + (e - N_X);        dst = Wqb + (e - N_X); }
    else                     { src = Wp + (e - N_X - N_WQ); dst = Wpb + (e - N_X - N_WQ); }
    *(v8bf*)dst = cvt8(src);
}

// ---------------------------------------------------------------------------
// Kernel 1: qkv = xb @ Wqkvb^T (m97 structure, unchanged).
// ---------------------------------------------------------------------------
__global__ __launch_bounds__(256) void qkv_gemm(
        const __bf16* __restrict__ xb, const __bf16* __restrict__ Wb,
        __bf16* __restrict__ Qb, __bf16* __restrict__ Kb, __bf16* __restrict__ Vtb) {
    __shared__ __bf16 As[128 * 32], Bs[128 * 32];
    const int lane = threadIdx.x & 63, wave = threadIdx.x >> 6;
    const int nb = blockIdx.x % 18, mb = blockIdx.x / 18;
    const int r16 = lane & 15, quad = lane >> 4;
    const int wm = (wave >> 1) * 64, wn = (wave & 1) * 64;
    const __bf16* Asrc = xb + (size_t)mb * 128 * DMODEL;
    const __bf16* Bsrc = Wb + (size_t)nb * 128 * DMODEL;

    v4f acc[4][4] = {};
    for (int k0 = 0; k0 < DMODEL; k0 += 32) {
#pragma unroll
        for (int p = 0; p < 2; ++p) {
            const int cb = p * 256 + wave * 64;
            const int c = cb + lane;
            const int row = c >> 2, sg = c & 3;
            async_copy16(&As[cb * 8], Asrc + (size_t)row * DMODEL + k0 + sg * 8);
            async_copy16(&Bs[cb * 8], Bsrc + (size_t)row * DMODEL + k0 + sg * 8);
        }
        __syncthreads();
        v8bf a[4], b[4];
#pragma unroll
        for (int i = 0; i < 4; ++i)
            a[i] = *(const v8bf*)&As[(wm + 16 * i + r16) * 32 + quad * 8];
#pragma unroll
        for (int j = 0; j < 4; ++j)
            b[j] = *(const v8bf*)&Bs[(wn + 16 * j + r16) * 32 + quad * 8];
#pragma unroll
        for (int i = 0; i < 4; ++i)
#pragma unroll
            for (int j = 0; j < 4; ++j)
                acc[i][j] = __builtin_amdgcn_mfma_f32_16x16x32_bf16(
                    a[i], b[j], acc[i][j], 0, 0, 0);
        __syncthreads();
    }

    const int seg = nb / 6;
    const int nl0 = (nb % 6) * 128 + wn;
#pragma unroll
    for (int j = 0; j < 4; ++j) {
        const int n = nl0 + 16 * j + r16;
        const int h = n >> 6, d = n & 63;
#pragma unroll
        for (int i = 0; i < 4; ++i) {
            const int mrow = mb * 128 + wm + 16 * i + quad * 4;
#pragma unroll
            for (int r = 0; r < 4; ++r) {
                const int m = mrow + r;
                const int bidx = m >> 11, t = m & (SEQ - 1);
                const size_t base = ((size_t)(bidx * NH + h)) * SEQ * DHEAD;
                if (seg == 0)
                    Qb[base + (size_t)t * DHEAD + d] = (__bf16)(acc[i][j][r] * SCALE_LOG2E);
                else if (seg == 1)
                    Kb[base + (size_t)t * DHEAD + d] = (__bf16)acc[i][j][r];
                else
                    Vtb[base + (size_t)d * SEQ + t] = (__bf16)acc[i][j][r];
            }
        }
    }
}

// ---------------------------------------------------------------------------
// Kernel 2: MFMA causal flash attention, R5 structure.
// Block = 4 waves x 32 q-rows = 128 rows. K/V chunk (64 keys) staged in LDS
// (shared by all waves), software-pipelined: frags->regs between barriers,
// next chunk's asyncs issued before compute. Fixed-max softmax, ones-MFMA l.
// blockIdx = qb*48 + bh  ->  XCD = bh%8 (48 = 0 mod 8): K/V L2-resident.
// ---------------------------------------------------------------------------
__global__ __launch_bounds__(256, 3) void attn_kernel(
        const __bf16* __restrict__ Qb, const __bf16* __restrict__ Kb,
        const __bf16* __restrict__ Vtb, __bf16* __restrict__ attnb) {
    __shared__ __bf16 Ks[2][64 * 32];               // [kk][key*32 + k] 8 KB
    __shared__ __bf16 Vs[2][64 * 32];               // [kk][d*32 + t]   8 KB
    __shared__ __align__(16) __bf16 Pl[4][32 * 72]; // per-wave P       18 KB
    const int lane = threadIdx.x & 63;
    const int wave = threadIdx.x >> 6;
    const int bh = blockIdx.x % 48;
    const int qt = 15 - (blockIdx.x / 48);           // longest first
    const int q0 = qt * 128 + wave * 32;
    const int r16 = lane & 15, quad = lane >> 4;

    const __bf16* Q  = Qb  + (size_t)bh * SEQ * DHEAD;
    const __bf16* K  = Kb  + (size_t)bh * SEQ * DHEAD;
    const __bf16* Vt = Vtb + (size_t)bh * DHEAD * SEQ;

    // staging map: thread covers LDS elems [wave*512 + lane*8 .. +8)
    const int srow  = wave * 16 + (lane >> 2);       // 0..63
    const int skoff = (lane & 3) * 8;                // 0,8,16,24
    __bf16* kd0 = &Ks[0][wave * 512];
    __bf16* kd1 = &Ks[1][wave * 512];
    __bf16* vd0 = &Vs[0][wave * 512];
    __bf16* vd1 = &Vs[1][wave * 512];

    v8bf aq[2][2];
#pragma unroll
    for (int i = 0; i < 2; ++i)
#pragma unroll
        for (int kk = 0; kk < 2; ++kk)
            aq[i][kk] = *(const v8bf*)(Q + (size_t)(q0 + 16 * i + r16) * DHEAD
                                         + kk * 32 + quad * 8);

    v8bf vones;
#pragma unroll
    for (int j = 0; j < 8; ++j) vones[j] = (__bf16)1.0f;

    v4f oacc[2][4] = {};
    v4f lacc[2] = {};

    const int nchunks = 2 * (qt + 1);
    // prefetch chunk 0
    async_copy16(kd0, K + (size_t)srow * DHEAD + skoff);
    async_copy16(kd1, K + (size_t)srow * DHEAD + 32 + skoff);
    async_copy16(vd0, Vt + (size_t)srow * SEQ + skoff);
    async_copy16(vd1, Vt + (size_t)srow * SEQ + 32 + skoff);

    for (int c = 0; c < nchunks; ++c) {
        const int k0 = c * 64;
        __syncthreads();                             // chunk-c copies landed
        v8bf bk[4][2], bv[2][4];
#pragma unroll
        for (int s = 0; s < 4; ++s)
#pragma unroll
            for (int kk = 0; kk < 2; ++kk)
                bk[s][kk] = *(const v8bf*)&Ks[kk][(16 * s + r16) * 32 + quad * 8];
#pragma unroll
        for (int kk = 0; kk < 2; ++kk)
#pragma unroll
            for (int n = 0; n < 4; ++n)
                bv[kk][n] = *(const v8bf*)&Vs[kk][(16 * n + r16) * 32 + quad * 8];
        __syncthreads();                             // frags in regs, LDS free
        if (c + 1 < nchunks) {                       // prefetch next chunk now
            const int k1 = k0 + 64;
            async_copy16(kd0, K + (size_t)(k1 / 64 * 64 + srow) * DHEAD + skoff);
            async_copy16(kd1, K + (size_t)(k1 / 64 * 64 + srow) * DHEAD + 32 + skoff);
            async_copy16(vd0, Vt + (size_t)srow * SEQ + k1 + skoff);
            async_copy16(vd1, Vt + (size_t)srow * SEQ + k1 + 32 + skoff);
        }
        if (k0 > q0 + 31) continue;                  // fully masked for this wave

        // ---- QK^T ----
        v4f sc[2][4] = {};
#pragma unroll
        for (int kk = 0; kk < 2; ++kk)
#pragma unroll
            for (int i = 0; i < 2; ++i)
#pragma unroll
                for (int s = 0; s < 4; ++s)
                    sc[i][s] = __builtin_amdgcn_mfma_f32_16x16x32_bf16(
                        aq[i][kk], bk[s][kk], sc[i][s], 0, 0, 0);

        // ---- causal mask (diagonal chunks only) ----
        if (k0 + 63 > q0) {
#pragma unroll
            for (int i = 0; i < 2; ++i)
#pragma unroll
                for (int s = 0; s < 4; ++s)
#pragma unroll
                    for (int r = 0; r < 4; ++r) {
                        const int row = q0 + 16 * i + quad * 4 + r;
                        const int col = k0 + 16 * s + r16;
                        if (col > row) sc[i][s][r] = -1e30f;
                    }
        }

        // ---- fixed-max softmax: p = exp2(s - 32) ----
#pragma unroll
        for (int i = 0; i < 2; ++i)
#pragma unroll
            for (int s = 0; s < 4; ++s)
#pragma unroll
                for (int r = 0; r < 4; ++r)
                    sc[i][s][r] = __builtin_exp2f(sc[i][s][r] - 32.0f);

        // ---- P: C-layout regs -> per-wave LDS (bf16) ----
#pragma unroll
        for (int i = 0; i < 2; ++i)
#pragma unroll
            for (int s = 0; s < 4; ++s)
#pragma unroll
                for (int r = 0; r < 4; ++r)
                    Pl[wave][(16 * i + quad * 4 + r) * 72 + 16 * s + r16] =
                        (__bf16)sc[i][s][r];
        __builtin_amdgcn_s_waitcnt(0);               // wave-internal LDS ordering

        // ---- PV + l (ones-MFMA) ----
        v8bf ap[2][2];
#pragma unroll
        for (int i = 0; i < 2; ++i)
#pragma unroll
            for (int kk = 0; kk < 2; ++kk)
                ap[i][kk] = *(const v8bf*)&Pl[wave][(16 * i + r16) * 72 + kk * 32 + quad * 8];
#pragma unroll
        for (int kk = 0; kk < 2; ++kk)
#pragma unroll
            for (int i = 0; i < 2; ++i) {
#pragma unroll
                for (int n = 0; n < 4; ++n)
                    oacc[i][n] = __builtin_amdgcn_mfma_f32_16x16x32_bf16(
                        ap[i][kk], bv[kk][n], oacc[i][n], 0, 0, 0);
                lacc[i] = __builtin_amdgcn_mfma_f32_16x16x32_bf16(
                    ap[i][kk], vones, lacc[i], 0, 0, 0);
            }
    }

    // ---- epilogue: O / l, scatter to [B,T,D] bf16 ----
    const int b = bh / NH, h = bh - b * NH;
#pragma unroll
    for (int i = 0; i < 2; ++i)
#pragma unroll
        for (int r = 0; r < 4; ++r) {
            const float inv = 1.0f / lacc[i][r];
            const int t = q0 + 16 * i + quad * 4 + r;
#pragma unroll
            for (int n = 0; n < 4; ++n) {
                const int d = 16 * n + r16;
                attnb[((size_t)(b * SEQ + t)) * DMODEL + h * DHEAD + d] =
                    (__bf16)(oacc[i][n][r] * inv);
            }
        }
}

// ---------------------------------------------------------------------------
// Kernel 3: out = attnb @ Wprojb^T + bproj (m97 structure, unchanged).
// ---------------------------------------------------------------------------
__global__ __launch_bounds__(256) void proj_gemm(
        const __bf16* __restrict__ Ab, const __bf16* __restrict__ Wb,
        const float* __restrict__ bias, float* __restrict__ out) {
    __shared__ __bf16 As[128 * 32], Bs[128 * 32];
    const int lane = threadIdx.x & 63, wave = threadIdx.x >> 6;
    const int nb = blockIdx.x % 6, mb = blockIdx.x / 6;
    const int r16 = lane & 15, quad = lane >> 4;
    const int wm = (wave >> 1) * 64, wn = (wave & 1) * 64;
    const __bf16* Asrc = Ab + (size_t)mb * 128 * DMODEL;
    const __bf16* Bsrc = Wb + (size_t)nb * 128 * DMODEL;

    v4f acc[4][4] = {};
    for (int k0 = 0; k0 < DMODEL; k0 += 32) {
#pragma unroll
        for (int p = 0; p < 2; ++p) {
            const int cb = p * 256 + wave * 64;
            const int c = cb + lane;
            const int row = c >> 2, sg = c & 3;
            async_copy16(&As[cb * 8], Asrc + (size_t)row * DMODEL + k0 + sg * 8);
            async_copy16(&Bs[cb * 8], Bsrc + (size_t)row * DMODEL + k0 + sg * 8);
        }
        __syncthreads();
        v8bf a[4], b[4];
#pragma unroll
        for (int i = 0; i < 4; ++i)
            a[i] = *(const v8bf*)&As[(wm + 16 * i + r16) * 32 + quad * 8];
#pragma unroll
        for (int j = 0; j < 4; ++j)
            b[j] = *(const v8bf*)&Bs[(wn + 16 * j + r16) * 32 + quad * 8];
#pragma unroll
        for (int i = 0; i < 4; ++i)
#pragma unroll
            for (int j = 0; j < 4; ++j)
                acc[i][j] = __builtin_amdgcn_mfma_f32_16x16x32_bf16(
                    a[i], b[j], acc[i][j], 0, 0, 0);
        __syncthreads();
    }

#pragma unroll
    for (int j = 0; j < 4; ++j) {
        const int n = nb * 128 + wn + 16 * j + r16;
        const float bv = bias[n];
#pragma unroll
        for (int i = 0; i < 4; ++i) {
            const int mrow = mb * 128 + wm + 16 * i + quad * 4;
#pragma unroll
            for (int r = 0; r < 4; ++r)
                out[(size_t)(mrow + r) * DMODEL + n] = acc[i][j][r] + bv;
        }
    }
}

// ---------------------------------------------------------------------------
extern "C" void kernel_launch(void* const* d_in, const int* in_sizes, int n_in,
                              void* d_out, int out_size, void* d_ws, size_t ws_size,
                              hipStream_t stream) {
    const float* x     = (const float*)d_in[0];
    const float* Wqkv  = (const float*)d_in[1];
    const float* Wproj = (const float*)d_in[2];
    const float* bproj = (const float*)d_in[3];
    float* out = (float*)d_out;

    char* ws = (char*)d_ws;
    const size_t tsz = (size_t)BATCH * NH * SEQ * DHEAD * sizeof(__bf16); // 12.58 MB
    __bf16* Qb    = (__bf16*)(ws);
    __bf16* Kb    = (__bf16*)(ws + tsz);
    __bf16* Vtb   = (__bf16*)(ws + 2 * tsz);          // [B,H,DH,T]
    __bf16* xb    = (__bf16*)(ws + 3 * tsz);          // aliased with attnb:
    __bf16* attnb = (__bf16*)(ws + 3 * tsz);          // xb dead before attn writes
    __bf16* Wqb   = (__bf16*)(ws + 4 * tsz);
    __bf16* Wpb   = (__bf16*)(ws + 4 * tsz + (size_t)N_WQ * 2);

    cvt_kernel<<<dim3((N_X + N_WQ + N_WP) / (8 * 256)), dim3(256), 0, stream>>>(
        x, Wqkv, Wproj, xb, Wqb, Wpb);
    qkv_gemm<<<dim3(64 * 18), dim3(256), 0, stream>>>(xb, Wqb, Qb, Kb, Vtb);
    attn_kernel<<<dim3(16 * 48), dim3(256), 0, stream>>>(Qb, Kb, Vtb, attnb);
    proj_gemm<<<dim3(64 * 6), dim3(256), 0, stream>>>(attnb, Wpb, bproj, out);
}

// Round 6
// 233.382 us; speedup vs baseline: 1.2846x; 1.0266x over previous
//
#include <hip/hip_runtime.h>
#include <hip/hip_bf16.h>

// B=4, T=2048, D=768, H=12, DH=64, causal MHA + QKV/out projections.
// All inputs fp32; internals bf16 (threshold 8*bf16eps permits this).
//
// R6: GEMMs get (a) true double-buffered global_load_lds staging with ONE
// barrier per k-iter (prefetch chunk c+1 into the other buffer right after
// frags of chunk c are read to regs — WAR-safe via the top-of-iter barrier),
// (b) XOR-swizzled LDS k-groups so ds_read_b128 is 2-way (free) instead of
// 8-way bank conflicted. Attention kernel unchanged from R5.

#define BATCH  4
#define SEQ    2048
#define DMODEL 768
#define NH     12
#define DHEAD  64
static constexpr float SCALE_LOG2E = 0.125f * 1.4426950408889634f;

#define N_X  (8192 * 768)
#define N_WQ (2304 * 768)
#define N_WP (768 * 768)

typedef __bf16 v8bf __attribute__((ext_vector_type(8)));
typedef float  v4f  __attribute__((ext_vector_type(4)));

__device__ __forceinline__ v8bf cvt8(const float* __restrict__ p) {
    const float4 a = ((const float4*)p)[0];
    const float4 b = ((const float4*)p)[1];
    v8bf r;
    r[0] = (__bf16)a.x; r[1] = (__bf16)a.y; r[2] = (__bf16)a.z; r[3] = (__bf16)a.w;
    r[4] = (__bf16)b.x; r[5] = (__bf16)b.y; r[6] = (__bf16)b.z; r[7] = (__bf16)b.w;
    return r;
}

__device__ __forceinline__ void async_copy16(__bf16* lds, const __bf16* g) {
    __builtin_amdgcn_global_load_lds(
        (const __attribute__((address_space(1))) void*)g,
        (__attribute__((address_space(3))) void*)lds, 16, 0, 0);
}

// ---------------------------------------------------------------------------
// Kernel 0: fp32 -> bf16 convert of x, Wqkv, Wproj.
// ---------------------------------------------------------------------------
__global__ __launch_bounds__(256) void cvt_kernel(
        const float* __restrict__ x, const float* __restrict__ Wq,
        const float* __restrict__ Wp, __bf16* __restrict__ xb,
        __bf16* __restrict__ Wqb, __bf16* __restrict__ Wpb) {
    const long e = ((long)blockIdx.x * 256 + threadIdx.x) * 8;
    const float* src;
    __bf16* dst;
    if (e < N_X)             { src = x  + e;               dst = xb  + e; }
    else if (e < N_X + N_WQ) { src = Wq + (e - N_X);        dst = Wqb + (e - N_X); }
    else                     { src = Wp + (e - N_X - N_WQ); dst = Wpb + (e - N_X - N_WQ); }
    *(v8bf*)dst = cvt8(src);
}

// ---------------------------------------------------------------------------
// Kernel 1: qkv = xb @ Wqkvb^T (M=8192, N=2304, K=768).
// Double-buffered LDS staging, swizzled k-groups, 1 barrier/iter.
// ---------------------------------------------------------------------------
__global__ __launch_bounds__(256) void qkv_gemm(
        const __bf16* __restrict__ xb, const __bf16* __restrict__ Wb,
        __bf16* __restrict__ Qb, __bf16* __restrict__ Kb, __bf16* __restrict__ Vtb) {
    __shared__ __bf16 As[2][128 * 32], Bs[2][128 * 32];   // 32 KB
    const int lane = threadIdx.x & 63, wave = threadIdx.x >> 6;
    const int nb = blockIdx.x % 18, mb = blockIdx.x / 18;
    const int r16 = lane & 15, quad = lane >> 4;
    const int wm = (wave >> 1) * 64, wn = (wave & 1) * 64;
    const __bf16* Asrc = xb + (size_t)mb * 128 * DMODEL;
    const __bf16* Bsrc = Wb + (size_t)nb * 128 * DMODEL;

    // staging: lane covers LDS slot (row, sg); fetches swizzled k-group g.
    const int srow = wave * 16 + (lane >> 2);         // rows 0..63 (p=0), +64 (p=1)
    const int sg   = lane & 3;
    const int g    = sg ^ ((srow >> 1) & 3);          // same for p=1 (row+64)
    const size_t soff0 = (size_t)srow * DMODEL + g * 8;
    const size_t soff1 = (size_t)(srow + 64) * DMODEL + g * 8;
    const int ld0 = wave * 512;                       // elems
    const int ld1 = 2048 + wave * 512;
    // frag-read swizzled position (wave-uniform per thread across i/j)
    const int p_rd = quad ^ ((r16 >> 1) & 3);

    // prologue: chunk 0 -> buf 0
    async_copy16(&As[0][ld0], Asrc + soff0);
    async_copy16(&As[0][ld1], Asrc + soff1);
    async_copy16(&Bs[0][ld0], Bsrc + soff0);
    async_copy16(&Bs[0][ld1], Bsrc + soff1);

    v4f acc[4][4] = {};
    for (int c = 0; c < 24; ++c) {
        const int cur = c & 1;
        __syncthreads();                              // chunk c landed
        v8bf a[4], b[4];
#pragma unroll
        for (int i = 0; i < 4; ++i)
            a[i] = *(const v8bf*)&As[cur][(wm + 16 * i + r16) * 32 + p_rd * 8];
#pragma unroll
        for (int j = 0; j < 4; ++j)
            b[j] = *(const v8bf*)&Bs[cur][(wn + 16 * j + r16) * 32 + p_rd * 8];
        if (c + 1 < 24) {                             // prefetch into other buffer
            const int nxt = cur ^ 1;
            const size_t k1 = (c + 1) * 32;
            async_copy16(&As[nxt][ld0], Asrc + soff0 + k1);
            async_copy16(&As[nxt][ld1], Asrc + soff1 + k1);
            async_copy16(&Bs[nxt][ld0], Bsrc + soff0 + k1);
            async_copy16(&Bs[nxt][ld1], Bsrc + soff1 + k1);
        }
#pragma unroll
        for (int i = 0; i < 4; ++i)
#pragma unroll
            for (int j = 0; j < 4; ++j)
                acc[i][j] = __builtin_amdgcn_mfma_f32_16x16x32_bf16(
                    a[i], b[j], acc[i][j], 0, 0, 0);
    }

    const int seg = nb / 6;
    const int nl0 = (nb % 6) * 128 + wn;
#pragma unroll
    for (int j = 0; j < 4; ++j) {
        const int n = nl0 + 16 * j + r16;
        const int h = n >> 6, d = n & 63;
#pragma unroll
        for (int i = 0; i < 4; ++i) {
            const int mrow = mb * 128 + wm + 16 * i + quad * 4;
#pragma unroll
            for (int r = 0; r < 4; ++r) {
                const int m = mrow + r;
                const int bidx = m >> 11, t = m & (SEQ - 1);
                const size_t base = ((size_t)(bidx * NH + h)) * SEQ * DHEAD;
                if (seg == 0)
                    Qb[base + (size_t)t * DHEAD + d] = (__bf16)(acc[i][j][r] * SCALE_LOG2E);
                else if (seg == 1)
                    Kb[base + (size_t)t * DHEAD + d] = (__bf16)acc[i][j][r];
                else
                    Vtb[base + (size_t)d * SEQ + t] = (__bf16)acc[i][j][r];
            }
        }
    }
}

// ---------------------------------------------------------------------------
// Kernel 2: MFMA causal flash attention (unchanged from R5).
// ---------------------------------------------------------------------------
__global__ __launch_bounds__(256, 3) void attn_kernel(
        const __bf16* __restrict__ Qb, const __bf16* __restrict__ Kb,
        const __bf16* __restrict__ Vtb, __bf16* __restrict__ attnb) {
    __shared__ __bf16 Ks[2][64 * 32];
    __shared__ __bf16 Vs[2][64 * 32];
    __shared__ __align__(16) __bf16 Pl[4][32 * 72];
    const int lane = threadIdx.x & 63;
    const int wave = threadIdx.x >> 6;
    const int bh = blockIdx.x % 48;
    const int qt = 15 - (blockIdx.x / 48);
    const int q0 = qt * 128 + wave * 32;
    const int r16 = lane & 15, quad = lane >> 4;

    const __bf16* Q  = Qb  + (size_t)bh * SEQ * DHEAD;
    const __bf16* K  = Kb  + (size_t)bh * SEQ * DHEAD;
    const __bf16* Vt = Vtb + (size_t)bh * DHEAD * SEQ;

    const int srow  = wave * 16 + (lane >> 2);
    const int skoff = (lane & 3) * 8;
    __bf16* kd0 = &Ks[0][wave * 512];
    __bf16* kd1 = &Ks[1][wave * 512];
    __bf16* vd0 = &Vs[0][wave * 512];
    __bf16* vd1 = &Vs[1][wave * 512];

    v8bf aq[2][2];
#pragma unroll
    for (int i = 0; i < 2; ++i)
#pragma unroll
        for (int kk = 0; kk < 2; ++kk)
            aq[i][kk] = *(const v8bf*)(Q + (size_t)(q0 + 16 * i + r16) * DHEAD
                                         + kk * 32 + quad * 8);

    v8bf vones;
#pragma unroll
    for (int j = 0; j < 8; ++j) vones[j] = (__bf16)1.0f;

    v4f oacc[2][4] = {};
    v4f lacc[2] = {};

    const int nchunks = 2 * (qt + 1);
    async_copy16(kd0, K + (size_t)srow * DHEAD + skoff);
    async_copy16(kd1, K + (size_t)srow * DHEAD + 32 + skoff);
    async_copy16(vd0, Vt + (size_t)srow * SEQ + skoff);
    async_copy16(vd1, Vt + (size_t)srow * SEQ + 32 + skoff);

    for (int c = 0; c < nchunks; ++c) {
        const int k0 = c * 64;
        __syncthreads();
        v8bf bk[4][2], bv[2][4];
#pragma unroll
        for (int s = 0; s < 4; ++s)
#pragma unroll
            for (int kk = 0; kk < 2; ++kk)
                bk[s][kk] = *(const v8bf*)&Ks[kk][(16 * s + r16) * 32 + quad * 8];
#pragma unroll
        for (int kk = 0; kk < 2; ++kk)
#pragma unroll
            for (int n = 0; n < 4; ++n)
                bv[kk][n] = *(const v8bf*)&Vs[kk][(16 * n + r16) * 32 + quad * 8];
        __syncthreads();
        if (c + 1 < nchunks) {
            const int k1 = k0 + 64;
            async_copy16(kd0, K + (size_t)(k1 + srow) * DHEAD + skoff);
            async_copy16(kd1, K + (size_t)(k1 + srow) * DHEAD + 32 + skoff);
            async_copy16(vd0, Vt + (size_t)srow * SEQ + k1 + skoff);
            async_copy16(vd1, Vt + (size_t)srow * SEQ + k1 + 32 + skoff);
        }
        if (k0 > q0 + 31) continue;

        v4f sc[2][4] = {};
#pragma unroll
        for (int kk = 0; kk < 2; ++kk)
#pragma unroll
            for (int i = 0; i < 2; ++i)
#pragma unroll
                for (int s = 0; s < 4; ++s)
                    sc[i][s] = __builtin_amdgcn_mfma_f32_16x16x32_bf16(
                        aq[i][kk], bk[s][kk], sc[i][s], 0, 0, 0);

        if (k0 + 63 > q0) {
#pragma unroll
            for (int i = 0; i < 2; ++i)
#pragma unroll
                for (int s = 0; s < 4; ++s)
#pragma unroll
                    for (int r = 0; r < 4; ++r) {
                        const int row = q0 + 16 * i + quad * 4 + r;
                        const int col = k0 + 16 * s + r16;
                        if (col > row) sc[i][s][r] = -1e30f;
                    }
        }

#pragma unroll
        for (int i = 0; i < 2; ++i)
#pragma unroll
            for (int s = 0; s < 4; ++s)
#pragma unroll
                for (int r = 0; r < 4; ++r)
                    sc[i][s][r] = __builtin_exp2f(sc[i][s][r] - 32.0f);

#pragma unroll
        for (int i = 0; i < 2; ++i)
#pragma unroll
            for (int s = 0; s < 4; ++s)
#pragma unroll
                for (int r = 0; r < 4; ++r)
                    Pl[wave][(16 * i + quad * 4 + r) * 72 + 16 * s + r16] =
                        (__bf16)sc[i][s][r];
        __builtin_amdgcn_s_waitcnt(0);

        v8bf ap[2][2];
#pragma unroll
        for (int i = 0; i < 2; ++i)
#pragma unroll
            for (int kk = 0; kk < 2; ++kk)
                ap[i][kk] = *(const v8bf*)&Pl[wave][(16 * i + r16) * 72 + kk * 32 + quad * 8];
#pragma unroll
        for (int kk = 0; kk < 2; ++kk)
#pragma unroll
            for (int i = 0; i < 2; ++i) {
#pragma unroll
                for (int n = 0; n < 4; ++n)
                    oacc[i][n] = __builtin_amdgcn_mfma_f32_16x16x32_bf16(
                        ap[i][kk], bv[kk][n], oacc[i][n], 0, 0, 0);
                lacc[i] = __builtin_amdgcn_mfma_f32_16x16x32_bf16(
                    ap[i][kk], vones, lacc[i], 0, 0, 0);
            }
    }

    const int b = bh / NH, h = bh - b * NH;
#pragma unroll
    for (int i = 0; i < 2; ++i)
#pragma unroll
        for (int r = 0; r < 4; ++r) {
            const float inv = 1.0f / lacc[i][r];
            const int t = q0 + 16 * i + quad * 4 + r;
#pragma unroll
            for (int n = 0; n < 4; ++n) {
                const int d = 16 * n + r16;
                attnb[((size_t)(b * SEQ + t)) * DMODEL + h * DHEAD + d] =
                    (__bf16)(oacc[i][n][r] * inv);
            }
        }
}

// ---------------------------------------------------------------------------
// Kernel 3: out = attnb @ Wprojb^T + bproj, dbuf + swizzle, fp32 out.
// ---------------------------------------------------------------------------
__global__ __launch_bounds__(256) void proj_gemm(
        const __bf16* __restrict__ Ab, const __bf16* __restrict__ Wb,
        const float* __restrict__ bias, float* __restrict__ out) {
    __shared__ __bf16 As[2][128 * 32], Bs[2][128 * 32];
    const int lane = threadIdx.x & 63, wave = threadIdx.x >> 6;
    const int nb = blockIdx.x % 6, mb = blockIdx.x / 6;
    const int r16 = lane & 15, quad = lane >> 4;
    const int wm = (wave >> 1) * 64, wn = (wave & 1) * 64;
    const __bf16* Asrc = Ab + (size_t)mb * 128 * DMODEL;
    const __bf16* Bsrc = Wb + (size_t)nb * 128 * DMODEL;

    const int srow = wave * 16 + (lane >> 2);
    const int sg   = lane & 3;
    const int g    = sg ^ ((srow >> 1) & 3);
    const size_t soff0 = (size_t)srow * DMODEL + g * 8;
    const size_t soff1 = (size_t)(srow + 64) * DMODEL + g * 8;
    const int ld0 = wave * 512;
    const int ld1 = 2048 + wave * 512;
    const int p_rd = quad ^ ((r16 >> 1) & 3);

    async_copy16(&As[0][ld0], Asrc + soff0);
    async_copy16(&As[0][ld1], Asrc + soff1);
    async_copy16(&Bs[0][ld0], Bsrc + soff0);
    async_copy16(&Bs[0][ld1], Bsrc + soff1);

    v4f acc[4][4] = {};
    for (int c = 0; c < 24; ++c) {
        const int cur = c & 1;
        __syncthreads();
        v8bf a[4], b[4];
#pragma unroll
        for (int i = 0; i < 4; ++i)
            a[i] = *(const v8bf*)&As[cur][(wm + 16 * i + r16) * 32 + p_rd * 8];
#pragma unroll
        for (int j = 0; j < 4; ++j)
            b[j] = *(const v8bf*)&Bs[cur][(wn + 16 * j + r16) * 32 + p_rd * 8];
        if (c + 1 < 24) {
            const int nxt = cur ^ 1;
            const size_t k1 = (c + 1) * 32;
            async_copy16(&As[nxt][ld0], Asrc + soff0 + k1);
            async_copy16(&As[nxt][ld1], Asrc + soff1 + k1);
            async_copy16(&Bs[nxt][ld0], Bsrc + soff0 + k1);
            async_copy16(&Bs[nxt][ld1], Bsrc + soff1 + k1);
        }
#pragma unroll
        for (int i = 0; i < 4; ++i)
#pragma unroll
            for (int j = 0; j < 4; ++j)
                acc[i][j] = __builtin_amdgcn_mfma_f32_16x16x32_bf16(
                    a[i], b[j], acc[i][j], 0, 0, 0);
    }

#pragma unroll
    for (int j = 0; j < 4; ++j) {
        const int n = nb * 128 + wn + 16 * j + r16;
        const float bv = bias[n];
#pragma unroll
        for (int i = 0; i < 4; ++i) {
            const int mrow = mb * 128 + wm + 16 * i + quad * 4;
#pragma unroll
            for (int r = 0; r < 4; ++r)
                out[(size_t)(mrow + r) * DMODEL + n] = acc[i][j][r] + bv;
        }
    }
}

// ---------------------------------------------------------------------------
extern "C" void kernel_launch(void* const* d_in, const int* in_sizes, int n_in,
                              void* d_out, int out_size, void* d_ws, size_t ws_size,
                              hipStream_t stream) {
    const float* x     = (const float*)d_in[0];
    const float* Wqkv  = (const float*)d_in[1];
    const float* Wproj = (const float*)d_in[2];
    const float* bproj = (const float*)d_in[3];
    float* out = (float*)d_out;

    char* ws = (char*)d_ws;
    const size_t tsz = (size_t)BATCH * NH * SEQ * DHEAD * sizeof(__bf16); // 12.58 MB
    __bf16* Qb    = (__bf16*)(ws);
    __bf16* Kb    = (__bf16*)(ws + tsz);
    __bf16* Vtb   = (__bf16*)(ws + 2 * tsz);          // [B,H,DH,T]
    __bf16* xb    = (__bf16*)(ws + 3 * tsz);          // aliased with attnb:
    __bf16* attnb = (__bf16*)(ws + 3 * tsz);          // xb dead before attn writes
    __bf16* Wqb   = (__bf16*)(ws + 4 * tsz);
    __bf16* Wpb   = (__bf16*)(ws + 4 * tsz + (size_t)N_WQ * 2);

    cvt_kernel<<<dim3((N_X + N_WQ + N_WP) / (8 * 256)), dim3(256), 0, stream>>>(
        x, Wqkv, Wproj, xb, Wqb, Wpb);
    qkv_gemm<<<dim3(64 * 18), dim3(256), 0, stream>>>(xb, Wqb, Qb, Kb, Vtb);
    attn_kernel<<<dim3(16 * 48), dim3(256), 0, stream>>>(Qb, Kb, Vtb, attnb);
    proj_gemm<<<dim3(64 * 6), dim3(256), 0, stream>>>(attnb, Wpb, bproj, out);
}